// Round 14
// baseline (44.799 us; speedup 1.0000x reference)
//
#include <hip/hip_runtime.h>
#include <math.h>

#define F 1024
#define D 64
#define H 128

typedef float v2f __attribute__((ext_vector_type(2)));

// Prep: A[i][k] = sum_r node[i][r]*W1[r][k] + b1[k]
//       Bt[k][i] = sum_r node[i][r]*W1[64+r][k]   (transposed for coalesced hot-loop reads)
__global__ __launch_bounds__(128) void prep_kernel(
    const float* __restrict__ node, const float* __restrict__ W1,
    const float* __restrict__ b1,
    float* __restrict__ A, float* __restrict__ Bt) {
  const int i = blockIdx.x;
  const int k = threadIdx.x;  // 0..127
  __shared__ float n[D];
  if (k < D) n[k] = node[i * D + k];
  __syncthreads();
  float a = b1[k];
  float b = 0.f;
#pragma unroll
  for (int r = 0; r < D; ++r) {
    const float nv = n[r];
    a = fmaf(nv, W1[r * H + k], a);
    b = fmaf(nv, W1[(D + r) * H + k], b);
  }
  A[i * H + k] = a;
  Bt[k * F + i] = b;
}

// Pair kernel R14: block = FOUR output rows, 512 threads (8 waves); thread
// owns j = 2tid, 2tid+1 packed as v2f.  Each Bt load (8 B) now feeds
// 8 elements (4 rows x 2 j) -> L1 vector-load demand HALVES vs R13
// (2 B/elem -> 1 B/elem).  This tests the last unfalsified binder: per-CU
// L1/TA delivery (~41 B/cy of ~64 at rows=2 across ALL null variants).
// Grid 256 blocks = 1/CU, 2 waves/SIMD (R3 proved ~2 waves/SIMD suffices).
// Math per element identical to R13 (cross-row Montgomery rcp on row pairs
// (0,1) and (2,3)) -> absmax unchanged.
// gelu_tanh(x) = x * rcp(1 + exp2(x * (C1 + C2*x^2)))
// C1 = -2*sqrt(2/pi)*log2(e), C2 = C1*0.044715.
// logits[i,j] = sum_k w2[k]*gelu(A[i,k]+Bt[k,j]); b2 cancels in softmax.
#define C1 (-2.3022082f)
#define C2 (-0.10294323f)

__device__ __forceinline__ void gelu2_acc(float a0, float a1, v2f b, float wk,
                                          v2f& acc0, v2f& acc1) {
  const v2f X0 = a0 + b;
  const v2f X1 = a1 + b;
  const v2f U0 = X0 * X0;
  const v2f U1 = X1 * X1;
  const v2f P0 = __builtin_elementwise_fma((v2f)(C2), U0, (v2f)(C1));
  const v2f P1 = __builtin_elementwise_fma((v2f)(C2), U1, (v2f)(C1));
  const v2f Arg0 = X0 * P0;
  const v2f Arg1 = X1 * P1;
  v2f E0, E1;
  E0.x = __builtin_amdgcn_exp2f(Arg0.x);
  E0.y = __builtin_amdgcn_exp2f(Arg0.y);
  E1.x = __builtin_amdgcn_exp2f(Arg1.x);
  E1.y = __builtin_amdgcn_exp2f(Arg1.y);
  const v2f D0 = 1.0f + E0;
  const v2f D1 = 1.0f + E1;
  const v2f PR = D0 * D1;
  v2f R;
  R.x = __builtin_amdgcn_rcpf(PR.x);
  R.y = __builtin_amdgcn_rcpf(PR.y);
  const v2f S0 = D1 * R;   // 1/D0
  const v2f S1 = D0 * R;   // 1/D1
  acc0 = __builtin_elementwise_fma(wk * X0, S0, acc0);
  acc1 = __builtin_elementwise_fma(wk * X1, S1, acc1);
}

__global__ __launch_bounds__(512) void pair_kernel(
    const float* __restrict__ A, const float* __restrict__ Bt,
    const float* __restrict__ w2, float* __restrict__ out) {
  const int i0 = blockIdx.x * 4;
  const int tid = threadIdx.x;
  const int wv = tid >> 6;
  const int lane = tid & 63;

  __shared__ float redm[8][4];
  __shared__ float reds[8][4];

  const float* __restrict__ Ar = A + (size_t)i0 * H;  // 4 consecutive rows

  v2f acc0 = {0.f, 0.f};  // row i0
  v2f acc1 = {0.f, 0.f};  // row i0+1
  v2f acc2 = {0.f, 0.f};  // row i0+2
  v2f acc3 = {0.f, 0.f};  // row i0+3

  const v2f* bp = reinterpret_cast<const v2f*>(Bt) + tid;  // Bt[k][2*tid..]
#pragma unroll 8
  for (int k = 0; k < H; ++k) {
    const v2f b = bp[k * (F / 2)];
    const float a0 = Ar[k];            // uniform -> s_load
    const float a1 = Ar[H + k];        // uniform -> s_load
    const float a2 = Ar[2 * H + k];    // uniform -> s_load
    const float a3 = Ar[3 * H + k];    // uniform -> s_load
    const float wk = w2[k];            // uniform -> s_load
    gelu2_acc(a0, a1, b, wk, acc0, acc1);
    gelu2_acc(a2, a3, b, wk, acc2, acc3);
  }

  // ---- fused softmax per row (1024 logits each, 8 waves) ----
  float m0 = fmaxf(acc0.x, acc0.y);
  float m1 = fmaxf(acc1.x, acc1.y);
  float m2 = fmaxf(acc2.x, acc2.y);
  float m3 = fmaxf(acc3.x, acc3.y);
#pragma unroll
  for (int off = 32; off >= 1; off >>= 1) {
    m0 = fmaxf(m0, __shfl_xor(m0, off, 64));
    m1 = fmaxf(m1, __shfl_xor(m1, off, 64));
    m2 = fmaxf(m2, __shfl_xor(m2, off, 64));
    m3 = fmaxf(m3, __shfl_xor(m3, off, 64));
  }
  if (lane == 0) {
    redm[wv][0] = m0;
    redm[wv][1] = m1;
    redm[wv][2] = m2;
    redm[wv][3] = m3;
  }
  __syncthreads();
  m0 = redm[0][0];
  m1 = redm[0][1];
  m2 = redm[0][2];
  m3 = redm[0][3];
#pragma unroll
  for (int w = 1; w < 8; ++w) {
    m0 = fmaxf(m0, redm[w][0]);
    m1 = fmaxf(m1, redm[w][1]);
    m2 = fmaxf(m2, redm[w][2]);
    m3 = fmaxf(m3, redm[w][3]);
  }

  float e00 = __expf(acc0.x - m0), e01 = __expf(acc0.y - m0);
  float e10 = __expf(acc1.x - m1), e11 = __expf(acc1.y - m1);
  float e20 = __expf(acc2.x - m2), e21 = __expf(acc2.y - m2);
  float e30 = __expf(acc3.x - m3), e31 = __expf(acc3.y - m3);
  float s0 = e00 + e01;
  float s1 = e10 + e11;
  float s2 = e20 + e21;
  float s3 = e30 + e31;
#pragma unroll
  for (int off = 32; off >= 1; off >>= 1) {
    s0 += __shfl_xor(s0, off, 64);
    s1 += __shfl_xor(s1, off, 64);
    s2 += __shfl_xor(s2, off, 64);
    s3 += __shfl_xor(s3, off, 64);
  }
  if (lane == 0) {
    reds[wv][0] = s0;
    reds[wv][1] = s1;
    reds[wv][2] = s2;
    reds[wv][3] = s3;
  }
  __syncthreads();
  s0 = 0.f;
  s1 = 0.f;
  s2 = 0.f;
  s3 = 0.f;
#pragma unroll
  for (int w = 0; w < 8; ++w) {
    s0 += reds[w][0];
    s1 += reds[w][1];
    s2 += reds[w][2];
    s3 += reds[w][3];
  }

  const float inv0 = __builtin_amdgcn_rcpf(s0);
  const float inv1 = __builtin_amdgcn_rcpf(s1);
  const float inv2 = __builtin_amdgcn_rcpf(s2);
  const float inv3 = __builtin_amdgcn_rcpf(s3);
  float2 o;
  o.x = e00 * inv0;
  o.y = e01 * inv0;
  *reinterpret_cast<float2*>(out + (size_t)(i0 + 0) * F + 2 * tid) = o;
  o.x = e10 * inv1;
  o.y = e11 * inv1;
  *reinterpret_cast<float2*>(out + (size_t)(i0 + 1) * F + 2 * tid) = o;
  o.x = e20 * inv2;
  o.y = e21 * inv2;
  *reinterpret_cast<float2*>(out + (size_t)(i0 + 2) * F + 2 * tid) = o;
  o.x = e30 * inv3;
  o.y = e31 * inv3;
  *reinterpret_cast<float2*>(out + (size_t)(i0 + 3) * F + 2 * tid) = o;
}

extern "C" void kernel_launch(void* const* d_in, const int* in_sizes, int n_in,
                              void* d_out, int out_size, void* d_ws, size_t ws_size,
                              hipStream_t stream) {
  const float* node = (const float*)d_in[0];  // [1024,64]
  const float* W1   = (const float*)d_in[1];  // [128,128]
  const float* b1   = (const float*)d_in[2];  // [128]
  const float* w2   = (const float*)d_in[3];  // [128]
  // d_in[4] = b2 : cancels in softmax, unused
  float* out = (float*)d_out;                 // [1024,1024]

  float* A  = (float*)d_ws;                   // [1024][128] = 512 KB
  float* Bt = A + (size_t)F * H;              // [128][1024] = 512 KB

  prep_kernel<<<F, H, 0, stream>>>(node, W1, b1, A, Bt);
  pair_kernel<<<F / 4, 512, 0, stream>>>(A, Bt, w2, out);
}